// Round 7
// baseline (108.531 us; speedup 1.0000x reference)
//
#include <hip/hip_runtime.h>
#include <hip/hip_bf16.h>

// Problem constants (fixed by reference)
#define BB  4
#define CC  64      // input channels
#define NN  4096    // W*H
#define CF  32      // f/g channels (CH/2)
#define CHN 64      // h channels

typedef __attribute__((ext_vector_type(8)))  __bf16 bf16x8;
typedef __attribute__((ext_vector_type(4)))  __bf16 bf16x4;
typedef __attribute__((ext_vector_type(4)))  float  floatx4;
typedef __attribute__((ext_vector_type(16))) float  floatx16;
typedef __attribute__((ext_vector_type(2)))  unsigned int uintx2;
typedef __attribute__((ext_vector_type(4)))  unsigned int uintx4;

__device__ __forceinline__ float scrub(float v) {
    return fminf(fmaxf(v, -1e30f), 1e30f);
}

// v_cvt_pk_bf16_f32: low16 = bf16(lo), high16 = bf16(hi). No builtin on
// gfx950 (guide T12) -> inline asm.
__device__ __forceinline__ unsigned cvt_pk_bf16(float lo, float hi) {
    unsigned r;
    asm("v_cvt_pk_bf16_f32 %0, %1, %2" : "=v"(r) : "v"(lo), "v"(hi));
    return r;
}

// ---------------------------------------------------------------------------
// SWIZZLED WORKSPACE LAYOUTS (r7): every attn load instruction reads a
// CONTIGUOUS 1KB panel (64 lanes x 16B, lane sub-offset (l31*2+hi)*16B)
// instead of 32 scattered 64B lines. Element->offset maps (bf16 elems):
//   fT/gT (n,c):  (n>>5)*1024 + (c>>4)*512 + (n&31)*16 + ((c>>3)&1)*8 + (c&7)
//   hvb  (ch,n):  (n>>6)*4096 + (ch>>5)*2048 + ((n>>4)&3)*512
//                 + (ch&31)*16 + ((n>>3)&1)*8 + (n&7)
// Totals per batch unchanged (256KB / 256KB / 512KB).
// ---------------------------------------------------------------------------

// ---------------------------------------------------------------------------
// Kernel 1: 1x1 convs as MFMA GEMM (r14/r15-verified math; r7 changes the
// STORE ADDRESSES only, per the swizzled layouts above).
// ---------------------------------------------------------------------------
__global__ __launch_bounds__(256) void prep_kernel(
    const float* __restrict__ x, const float* __restrict__ y,
    const float* __restrict__ Wf, const float* __restrict__ bfp,
    const float* __restrict__ Wg, const float* __restrict__ bgp,
    const float* __restrict__ Wh, const float* __restrict__ bhp,
    __bf16* __restrict__ fT, __bf16* __restrict__ gT, __bf16* __restrict__ hvb)
{
    __shared__ __align__(16) __bf16 wbf[128][72];
    __shared__ float sbias[128];

    const int t  = threadIdx.x;
    const int w  = t >> 6;
    const int l  = t & 63;
    const int lo = l & 15;
    const int q  = l >> 4;

    const int b   = blockIdx.x >> 6;
    const int nb  = blockIdx.x & 63;
    const int nn  = nb * 64 + w * 16 + lo;

    for (int i = t; i < 128 * CC; i += 256) {
        int row = i >> 6, c = i & 63;
        float wv;
        if (row < 32)      wv = Wf[(size_t)row * CC + c];
        else if (row < 64) wv = Wg[(size_t)(row - 32) * CC + c];
        else               wv = Wh[(size_t)(row - 64) * CC + c];
        wbf[row][c] = (__bf16)wv;
    }
    if (t < 128) {
        if (t < 32)      sbias[t] = bfp[t];
        else if (t < 64) sbias[t] = bgp[t - 32];
        else             sbias[t] = bhp[t - 64];
    }
    __syncthreads();

    const float* xb = x + (size_t)b * CC * NN;
    const float* yb = y + (size_t)b * CC * NN;
    bf16x8 bx[2], by[2];
    #pragma unroll
    for (int kh = 0; kh < 2; kh++) {
        #pragma unroll
        for (int j = 0; j < 8; j++) {
            int c = kh * 32 + q * 8 + j;
            bx[kh][j] = (__bf16)xb[(size_t)c * NN + nn];
            by[kh][j] = (__bf16)yb[(size_t)c * NN + nn];
        }
    }

    const floatx4 zero4 = {0.f, 0.f, 0.f, 0.f};
    #pragma unroll
    for (int ct = 0; ct < 8; ct++) {
        const bf16x8* src = (ct < 2) ? bx : by;
        floatx4 acc = zero4;
        #pragma unroll
        for (int kh = 0; kh < 2; kh++) {
            const bf16x8 a = *(const bf16x8*)&wbf[ct*16 + lo][kh*32 + q*8];
            acc = __builtin_amdgcn_mfma_f32_16x16x32_bf16(a, src[kh], acc, 0, 0, 0);
        }
        if (ct < 4) {
            bf16x4 pk;
            #pragma unroll
            for (int r = 0; r < 4; r++)
                pk[r] = (__bf16)(acc[r] + sbias[ct*16 + q*4 + r]);
            __bf16* dstbase = (ct < 2) ? fT : gT;
            const int c0 = (ct & 1) * 16 + q * 4;          // c0&7 in {0,4}
            const int off = (nn >> 5)*1024 + (c0 >> 4)*512 + (nn & 31)*16
                          + ((c0 >> 3) & 1)*8 + (c0 & 7);
            *(bf16x4*)&dstbase[(size_t)b * NN * CF + off] = pk;
        } else {
            #pragma unroll
            for (int r = 0; r < 4; r++) {
                int ch = (ct - 4) * 16 + q*4 + r;
                const int off = (nn >> 6)*4096 + (ch >> 5)*2048
                              + ((nn >> 4) & 3)*512 + (ch & 31)*16
                              + ((nn >> 3) & 1)*8 + (nn & 7);
                hvb[(size_t)b * CHN * NN + off] =
                    (__bf16)(acc[r] + sbias[64 + ch]);
            }
        }
    }
}

// ---------------------------------------------------------------------------
// Kernel 2: fused flash attention, r7 = ch-split + BM=128 + swizzled loads.
// Evidence (r1/r3/r4/r6 nulls, r2 win): attn time tracks ONLY per-CU VMEM
// volume/density. So:
//  (a) block = (b, 128-row m-tile, 32-ch half), grid 256 = 1 block/CU.
//      Per-CU reads 768KB -> 512KB (f full + hv half). QK/exp duplicated
//      across the 2 ch-halves (identical per-row arithmetic -> absmax
//      unchanged); PV only for own 32 ch (oacc[4] x 16 = 64 VGPR).
//  (b) all loads hit the swizzled layouts: each instr = contiguous 1KB
//      panel, lane offset (l31*2+hi)*16B -> 16 dense lines vs 32 scattered.
// Main loop: in-register P (r6-verified T12 path), zero LDS, zero fences.
// Per wave: 8 chunks of 64n x 128m: 4 af + 4 bv loads, 16 QK + 16 PV MFMA,
// 128 exp. Rowsum per-lane f32 on bf16-rounded P + shfl_xor(32) (r6 order).
// Merge: 8 parity slots, osum[8][128][33] f32 = 135,168B + lsum 4KB ->
// 139,264B LDS, 1 block/CU. Epilogue per block: 128m x own 32ch.
// XCD map: xcd = slot&7 -> (b = xcd>>1, chh = xcd&1); per-XCD L2 set ~1MB.
// ---------------------------------------------------------------------------
__global__ __launch_bounds__(512, 2) void attn_kernel(
    const __bf16* __restrict__ fT, const __bf16* __restrict__ gT,
    const __bf16* __restrict__ hvb,
    const float* __restrict__ x, const float* __restrict__ gamma_p,
    float* __restrict__ out)
{
    __shared__ float osum[8][128][33];  // 135,168 B
    __shared__ float lsum[1024];        //   4,096 B  [w*128 + m_local]

    const int t   = threadIdx.x;
    const int w   = t >> 6;               // wave = n-parity (0..7)
    const int l   = t & 63;
    const int l31 = l & 31;
    const int hi  = l >> 5;

    const int slot = blockIdx.x;          // 0..255
    const int xcd  = slot & 7;
    const int b    = xcd >> 1;            // batch on XCD pair
    const int chh  = xcd & 1;             // ch half (0: ch 0..31, 1: 32..63)
    const int mg   = slot >> 3;           // 0..31
    const int m0   = mg * 128;

    const __bf16* fb = fT  + (size_t)b * NN * CF;
    const __bf16* gb = gT  + (size_t)b * NN * CF;
    const __bf16* hb = hvb + (size_t)b * CHN * NN;

    const int lane16 = (l31 * 2 + hi) * 8;   // elem sub-offset in a 1KB panel

    // Hoisted QK B-operand: g-panels for the block's 4 m-subtiles.
    // B-frag 32x32x16: lane -> col m = l31, k c = kk*16 + hi*8 + j.
    bf16x8 bg_[4][2];
    #pragma unroll
    for (int mt = 0; mt < 4; mt++)
        #pragma unroll
        for (int kk = 0; kk < 2; kk++)
            bg_[mt][kk] = *(const bf16x8*)(gb + (size_t)(mg*4 + mt)*1024 + kk*512 + lane16);

    const floatx16 zero16 = {};
    floatx16 oacc[4];                     // [mt]: ch_l=l31, m=mt*32+crow(r,hi)
    #pragma unroll
    for (int mt = 0; mt < 4; mt++) oacc[mt] = zero16;
    float rsum[4] = {0.f, 0.f, 0.f, 0.f}; // partial rowsum for m=mt*32+l31

    for (int i = 0; i < 8; i++) {
        const int nc = 8*i + w;           // 64-wide n-chunk index (parity w)

        // QK A-operand: f-panels. A-frag: lane -> row n = l31, k as above.
        bf16x8 af[2][2];
        #pragma unroll
        for (int nt = 0; nt < 2; nt++)
            #pragma unroll
            for (int kk = 0; kk < 2; kk++)
                af[nt][kk] = *(const bf16x8*)(fb + (size_t)(nc*2 + nt)*1024 + kk*512 + lane16);

        // PV B-operand: hv panels for own ch-half. lane -> col ch_l = l31,
        // k n = ks*16 + hi*8 + j.
        bf16x8 bv[4];
        #pragma unroll
        for (int ks = 0; ks < 4; ks++)
            bv[ks] = *(const bf16x8*)(hb + (size_t)nc*4096 + chh*2048 + ks*512 + lane16);

        // ---- per m-subtile: QK + exp + in-register P (r6-verified), PV
        #pragma unroll
        for (int mt = 0; mt < 4; mt++) {
            bf16x8 pa[4];
            #pragma unroll
            for (int nt = 0; nt < 2; nt++) {
                floatx16 s = __builtin_amdgcn_mfma_f32_32x32x16_bf16(
                    af[nt][0], bg_[mt][0], zero16, 0, 0, 0);
                s = __builtin_amdgcn_mfma_f32_32x32x16_bf16(
                    af[nt][1], bg_[mt][1], s, 0, 0, 0);
                // lane holds S[m=mt*32+l31][n = nc*64+nt*32+crow(r,hi)]

                float p[16];
                #pragma unroll
                for (int r = 0; r < 16; r++) p[r] = __expf(s[r]);

                unsigned W[8];
                #pragma unroll
                for (int g = 0; g < 8; g++) W[g] = cvt_pk_bf16(p[2*g], p[2*g+1]);

                // rowsum on bf16-rounded values (numerator-consistent)
                #pragma unroll
                for (int g = 0; g < 8; g++)
                    rsum[mt] += __uint_as_float(W[g] << 16)
                              + __uint_as_float(W[g] & 0xffff0000u);

                // T12 swap network (r6-verified)
                uintx2 s02 = __builtin_amdgcn_permlane32_swap(W[0], W[2], false, false);
                uintx2 s13 = __builtin_amdgcn_permlane32_swap(W[1], W[3], false, false);
                uintx2 s46 = __builtin_amdgcn_permlane32_swap(W[4], W[6], false, false);
                uintx2 s57 = __builtin_amdgcn_permlane32_swap(W[5], W[7], false, false);

                uintx4 w0 = {s02.x, s13.x, s02.y, s13.y};   // n_local 0..15
                uintx4 w1 = {s46.x, s57.x, s46.y, s57.y};   // n_local 16..31
                pa[nt*2 + 0] = __builtin_bit_cast(bf16x8, w0);
                pa[nt*2 + 1] = __builtin_bit_cast(bf16x8, w1);
            }
            #pragma unroll
            for (int ks = 0; ks < 4; ks++)
                oacc[mt] = __builtin_amdgcn_mfma_f32_32x32x16_bf16(
                    pa[ks], bv[ks], oacc[mt], 0, 0, 0);
        }
    }

    // combine the two lane-halves' complementary n-sets
    #pragma unroll
    for (int mt = 0; mt < 4; mt++)
        rsum[mt] += __shfl_xor(rsum[mt], 32, 64);

    // ---- parallel merge across the 8 parity waves (r2/r6 order)
    #pragma unroll
    for (int mt = 0; mt < 4; mt++) {
        #pragma unroll
        for (int r = 0; r < 16; r++)
            osum[w][mt*32 + ((r&3) + 8*(r>>2) + 4*hi)][l31] = oacc[mt][r];
        if (hi == 0)
            lsum[w*128 + mt*32 + l31] = rsum[mt];
    }
    __syncthreads();

    // ---- 8-slot reduce + fused epilogue: out = gamma * osum/lsum + x
    const float gam = gamma_p[0];
    const int m  = t & 127;         // coalesced across lanes
    const int cb = t >> 7;          // 0..3
    float lt = 0.f;
    #pragma unroll
    for (int s = 0; s < 8; s++) lt += lsum[s*128 + m];
    const float inv = 1.f / lt;
    #pragma unroll
    for (int it = 0; it < 8; it++) {
        const int chl = it*4 + cb;                 // 0..31
        const int ch  = chh*32 + chl;
        float acc = 0.f;
        #pragma unroll
        for (int s = 0; s < 8; s++) acc += osum[s][m][chl];
        size_t gi = ((size_t)b * CHN + ch) * NN + m0 + m;
        float ov = scrub(acc * inv);
        out[gi] = gam * ov + x[gi];
    }
}

// ---------------------------------------------------------------------------
extern "C" void kernel_launch(void* const* d_in, const int* in_sizes, int n_in,
                              void* d_out, int out_size, void* d_ws, size_t ws_size,
                              hipStream_t stream)
{
    const float* x     = (const float*)d_in[0];
    const float* y     = (const float*)d_in[1];
    const float* Wf    = (const float*)d_in[2];
    const float* bf    = (const float*)d_in[3];
    const float* Wg    = (const float*)d_in[4];
    const float* bg    = (const float*)d_in[5];
    const float* Wh    = (const float*)d_in[6];
    const float* bh    = (const float*)d_in[7];
    const float* gamma = (const float*)d_in[8];
    float* out = (float*)d_out;

    __bf16* wsb = (__bf16*)d_ws;
    __bf16* fT  = wsb;                                // [4][swizzled 4096x32] = 1 MB
    __bf16* gT  = fT + (size_t)BB * NN * CF;          // 1 MB
    __bf16* hvb = gT + (size_t)BB * NN * CF;          // [4][swizzled 64x4096] = 2 MB
    // total 4 MB of ws

    prep_kernel<<<dim3(BB * 64), dim3(256), 0, stream>>>(
        x, y, Wf, bf, Wg, bg, Wh, bh, fT, gT, hvb);
    attn_kernel<<<dim3(BB * 64), dim3(512), 0, stream>>>(
        fT, gT, hvb, x, gamma, out);
}

// Round 8
// 100.495 us; speedup vs baseline: 1.0800x; 1.0800x over previous
//
#include <hip/hip_runtime.h>
#include <hip/hip_bf16.h>

// Problem constants (fixed by reference)
#define BB  4
#define CC  64      // input channels
#define NN  4096    // W*H
#define CF  32      // f/g channels (CH/2)
#define CHN 64      // h channels

typedef __attribute__((ext_vector_type(8)))  __bf16 bf16x8;
typedef __attribute__((ext_vector_type(4)))  __bf16 bf16x4;
typedef __attribute__((ext_vector_type(4)))  float  floatx4;
typedef __attribute__((ext_vector_type(16))) float  floatx16;
typedef __attribute__((ext_vector_type(2)))  unsigned int uintx2;
typedef __attribute__((ext_vector_type(4)))  unsigned int uintx4;

__device__ __forceinline__ float scrub(float v) {
    return fminf(fmaxf(v, -1e30f), 1e30f);
}

// v_cvt_pk_bf16_f32: low16 = bf16(lo), high16 = bf16(hi). No builtin on
// gfx950 (guide T12) -> inline asm.
__device__ __forceinline__ unsigned cvt_pk_bf16(float lo, float hi) {
    unsigned r;
    asm("v_cvt_pk_bf16_f32 %0, %1, %2" : "=v"(r) : "v"(lo), "v"(hi));
    return r;
}

// ---------------------------------------------------------------------------
// Kernel 1: 1x1 convs as MFMA GEMM. r8: occupancy doubled. Old geometry was
// 256 blocks x 256 thr = 1 block/CU, 1 wave/SIMD (worst latency hiding) and
// prep's cost was never measured (below fill in top-5). New: 512 blocks
// (b = bid>>7, nb = bid&127), each covering 32 nn; the 8 ct output tiles
// split across waves (w<2 -> ct 0..3 f/g, w>=2 -> ct 4..7 hv). Per-element
// math, store addresses, and summation order IDENTICAL to r6 -> bit-equal
// outputs. y-columns are loaded twice per nn (once per ct-half) = +4MB
// traffic, irrelevant vs the 2x wave-parallelism.
// ---------------------------------------------------------------------------
__global__ __launch_bounds__(256) void prep_kernel(
    const float* __restrict__ x, const float* __restrict__ y,
    const float* __restrict__ Wf, const float* __restrict__ bfp,
    const float* __restrict__ Wg, const float* __restrict__ bgp,
    const float* __restrict__ Wh, const float* __restrict__ bhp,
    __bf16* __restrict__ fT, __bf16* __restrict__ gT, __bf16* __restrict__ hvb)
{
    __shared__ __align__(16) __bf16 wbf[128][72];
    __shared__ float sbias[128];

    const int t  = threadIdx.x;
    const int w  = t >> 6;               // 0..3
    const int l  = t & 63;
    const int lo = l & 15;
    const int q  = l >> 4;

    const int b   = blockIdx.x >> 7;
    const int nb  = blockIdx.x & 127;
    const int nn  = nb * 32 + (w & 1) * 16 + lo;   // 32 nn per block
    const int ctbase = (w < 2) ? 0 : 4;            // ct-half per wave pair

    for (int i = t; i < 128 * CC; i += 256) {
        int row = i >> 6, c = i & 63;
        float wv;
        if (row < 32)      wv = Wf[(size_t)row * CC + c];
        else if (row < 64) wv = Wg[(size_t)(row - 32) * CC + c];
        else               wv = Wh[(size_t)(row - 64) * CC + c];
        wbf[row][c] = (__bf16)wv;
    }
    if (t < 128) {
        if (t < 32)      sbias[t] = bfp[t];
        else if (t < 64) sbias[t] = bgp[t - 32];
        else             sbias[t] = bhp[t - 64];
    }
    __syncthreads();

    const float* xb = x + (size_t)b * CC * NN;
    const float* yb = y + (size_t)b * CC * NN;
    bf16x8 bx[2], by[2];
    #pragma unroll
    for (int kh = 0; kh < 2; kh++) {
        #pragma unroll
        for (int j = 0; j < 8; j++) {
            int c = kh * 32 + q * 8 + j;
            by[kh][j] = (__bf16)yb[(size_t)c * NN + nn];
        }
    }
    if (w < 2) {        // bx only needed for ct 0,1
        #pragma unroll
        for (int kh = 0; kh < 2; kh++)
            #pragma unroll
            for (int j = 0; j < 8; j++) {
                int c = kh * 32 + q * 8 + j;
                bx[kh][j] = (__bf16)xb[(size_t)c * NN + nn];
            }
    }

    const floatx4 zero4 = {0.f, 0.f, 0.f, 0.f};
    #pragma unroll
    for (int cti = 0; cti < 4; cti++) {
        const int ct = ctbase + cti;
        const bf16x8* src = (ct < 2) ? bx : by;
        floatx4 acc = zero4;
        #pragma unroll
        for (int kh = 0; kh < 2; kh++) {
            const bf16x8 a = *(const bf16x8*)&wbf[ct*16 + lo][kh*32 + q*8];
            acc = __builtin_amdgcn_mfma_f32_16x16x32_bf16(a, src[kh], acc, 0, 0, 0);
        }
        if (ct < 4) {
            bf16x4 pk;
            #pragma unroll
            for (int r = 0; r < 4; r++)
                pk[r] = (__bf16)(acc[r] + sbias[ct*16 + q*4 + r]);
            __bf16* dstbase = (ct < 2) ? fT : gT;
            int cho = (ct & 1) * 16;
            *(bf16x4*)&dstbase[((size_t)b * NN + nn) * CF + cho + q*4] = pk;
        } else {
            #pragma unroll
            for (int r = 0; r < 4; r++) {
                int ch = (ct - 4) * 16 + q*4 + r;
                hvb[((size_t)b * CHN + ch) * NN + nn] =
                    (__bf16)(acc[r] + sbias[64 + ch]);
            }
        }
    }
}

// ---------------------------------------------------------------------------
// Kernel 2: fused flash attention — EXACT r6 revert (best total, 102.3us).
// 32x32 swapped-QK + in-register P (T12), zero LDS / zero fences in loop.
// Grid BB*64, 512 thr, 8 n-parity waves, 64-row m-tile, 1 block/CU.
// r7's ch-split (+6us VALU regression) and swizzled layouts reverted.
// ---------------------------------------------------------------------------
__global__ __launch_bounds__(512, 2) void attn_kernel(
    const __bf16* __restrict__ fT, const __bf16* __restrict__ gT,
    const __bf16* __restrict__ hvb,
    const float* __restrict__ x, const float* __restrict__ gamma_p,
    float* __restrict__ out)
{
    __shared__ float osum[8][64][67];   // 137,216 B
    __shared__ float lsum[512];         //   2,048 B  [w*64 + m]

    const int t   = threadIdx.x;
    const int w   = t >> 6;               // wave = n-parity (0..7)
    const int l   = t & 63;
    const int l31 = l & 31;
    const int hi  = l >> 5;

    // XCD swizzle (r3, harmless): XCD pair (2b,2b+1) serves batch b.
    const int slot = blockIdx.x;          // 0..255
    const int xcd  = slot & 7;
    const int b    = xcd >> 1;
    const int mg   = ((xcd & 1) << 5) | (slot >> 3);   // 0..63
    const int m0   = mg * 64;

    const __bf16* fb = fT  + (size_t)b * NN * CF;
    const __bf16* gb = gT  + (size_t)b * NN * CF;
    const __bf16* hb = hvb + (size_t)b * CHN * NN;

    // Hoisted QK B-operand: g[m][c] fragments. B-frag 32x32x16: lane ->
    // col m = l31, k c = hi*8+j (+kk*16). Contiguous 16 B/lane.
    bf16x8 bg_[2][2];
    #pragma unroll
    for (int mt = 0; mt < 2; mt++)
        #pragma unroll
        for (int kk = 0; kk < 2; kk++)
            bg_[mt][kk] = *(const bf16x8*)(gb + (size_t)(m0 + mt*32 + l31) * CF + kk*16 + hi*8);

    const floatx16 zero16 = {};
    floatx16 oacc[2][2];                  // [mt][ct]: ch=ct*32+l31, m=mt*32+crow(r,hi)
    #pragma unroll
    for (int mt = 0; mt < 2; mt++)
        #pragma unroll
        for (int ct = 0; ct < 2; ct++) oacc[mt][ct] = zero16;
    float rsum[2] = {0.f, 0.f};           // per-lane partial rowsum for m=mt*32+l31

    for (int i = 0; i < 8; i++) {
        const int n0 = (8*i + w) * 64;

        // QK A-operand: f[n][c]. A-frag: lane -> row n = l31, k c = hi*8+j.
        bf16x8 af[2][2];
        #pragma unroll
        for (int nt = 0; nt < 2; nt++)
            #pragma unroll
            for (int kk = 0; kk < 2; kk++)
                af[nt][kk] = *(const bf16x8*)(fb + (size_t)(n0 + nt*32 + l31) * CF + kk*16 + hi*8);

        // PV B-operand: hv^T[n][ch]. B-frag: lane -> col ch = l31, k n =
        // ks*16 + hi*8 + j. 16 B/lane, rows NN apart.
        bf16x8 bv[2][4];
        #pragma unroll
        for (int ct = 0; ct < 2; ct++)
            #pragma unroll
            for (int ks = 0; ks < 4; ks++)
                bv[ct][ks] = *(const bf16x8*)(hb + (size_t)(ct*32 + l31) * NN + n0 + ks*16 + hi*8);

        // ---- QK + exp + in-register P build
        bf16x8 pa[2][4];                  // [mt][ks]: PV A-frags
        #pragma unroll
        for (int mt = 0; mt < 2; mt++) {
            #pragma unroll
            for (int nt = 0; nt < 2; nt++) {
                floatx16 s = __builtin_amdgcn_mfma_f32_32x32x16_bf16(
                    af[nt][0], bg_[mt][0], zero16, 0, 0, 0);
                s = __builtin_amdgcn_mfma_f32_32x32x16_bf16(
                    af[nt][1], bg_[mt][1], s, 0, 0, 0);
                // lane holds S[m=mt*32+l31][n = n0+nt*32+crow(r,hi)]

                float p[16];
                #pragma unroll
                for (int r = 0; r < 16; r++) p[r] = __expf(s[r]);

                unsigned W[8];
                #pragma unroll
                for (int g = 0; g < 8; g++) W[g] = cvt_pk_bf16(p[2*g], p[2*g+1]);

                // rowsum over this lane's 16 n's, on bf16-rounded values
                // (consistent with the PV numerator)
                #pragma unroll
                for (int g = 0; g < 8; g++)
                    rsum[mt] += __uint_as_float(W[g] << 16)
                              + __uint_as_float(W[g] & 0xffff0000u);

                // T12 swap network: one permlane32_swap fills two words.
                uintx2 s02 = __builtin_amdgcn_permlane32_swap(W[0], W[2], false, false);
                uintx2 s13 = __builtin_amdgcn_permlane32_swap(W[1], W[3], false, false);
                uintx2 s46 = __builtin_amdgcn_permlane32_swap(W[4], W[6], false, false);
                uintx2 s57 = __builtin_amdgcn_permlane32_swap(W[5], W[7], false, false);

                uintx4 w0 = {s02.x, s13.x, s02.y, s13.y};   // n_local 0..15
                uintx4 w1 = {s46.x, s57.x, s46.y, s57.y};   // n_local 16..31
                pa[mt][nt*2 + 0] = __builtin_bit_cast(bf16x8, w0);
                pa[mt][nt*2 + 1] = __builtin_bit_cast(bf16x8, w1);
            }
        }

        // ---- PV: O[m][ch] += sum_n P[m][n] hv[ch][n]
        #pragma unroll
        for (int mt = 0; mt < 2; mt++)
            #pragma unroll
            for (int ct = 0; ct < 2; ct++)
                #pragma unroll
                for (int ks = 0; ks < 4; ks++)
                    oacc[mt][ct] = __builtin_amdgcn_mfma_f32_32x32x16_bf16(
                        pa[mt][ks], bv[ct][ks], oacc[mt][ct], 0, 0, 0);
    }

    // combine the two lane-halves' complementary n-sets
    #pragma unroll
    for (int mt = 0; mt < 2; mt++)
        rsum[mt] += __shfl_xor(rsum[mt], 32, 64);

    // ---- parallel merge across the 8 parity waves (r2 pattern)
    #pragma unroll
    for (int mt = 0; mt < 2; mt++) {
        #pragma unroll
        for (int ct = 0; ct < 2; ct++)
            #pragma unroll
            for (int r = 0; r < 16; r++)
                osum[w][mt*32 + ((r&3) + 8*(r>>2) + 4*hi)][ct*32 + l31] =
                    oacc[mt][ct][r];
        if (hi == 0)
            lsum[w*64 + mt*32 + l31] = rsum[mt];
    }
    __syncthreads();

    // ---- 8-slot reduce + fused epilogue: out = gamma * osum/lsum + x
    const float gam = gamma_p[0];
    const int m  = t & 63;          // coalesced across lanes (full wave = 64 m)
    const int cb = t >> 6;          // 0..7
    float lt = 0.f;
    #pragma unroll
    for (int s = 0; s < 8; s++) lt += lsum[s*64 + m];
    const float inv = 1.f / lt;
    #pragma unroll
    for (int it = 0; it < 8; it++) {
        const int ch = it*8 + cb;
        float acc = 0.f;
        #pragma unroll
        for (int s = 0; s < 8; s++) acc += osum[s][m][ch];
        size_t gi = ((size_t)b * CHN + ch) * NN + m0 + m;
        float ov = scrub(acc * inv);
        out[gi] = gam * ov + x[gi];
    }
}

// ---------------------------------------------------------------------------
extern "C" void kernel_launch(void* const* d_in, const int* in_sizes, int n_in,
                              void* d_out, int out_size, void* d_ws, size_t ws_size,
                              hipStream_t stream)
{
    const float* x     = (const float*)d_in[0];
    const float* y     = (const float*)d_in[1];
    const float* Wf    = (const float*)d_in[2];
    const float* bf    = (const float*)d_in[3];
    const float* Wg    = (const float*)d_in[4];
    const float* bg    = (const float*)d_in[5];
    const float* Wh    = (const float*)d_in[6];
    const float* bh    = (const float*)d_in[7];
    const float* gamma = (const float*)d_in[8];
    float* out = (float*)d_out;

    __bf16* wsb = (__bf16*)d_ws;
    __bf16* fT  = wsb;                                // [4][4096][32] bf16 = 1 MB
    __bf16* gT  = fT + (size_t)BB * NN * CF;          // 1 MB
    __bf16* hvb = gT + (size_t)BB * NN * CF;          // [4][64][4096] bf16 = 2 MB
    // total 4 MB of ws

    prep_kernel<<<dim3(BB * 128), dim3(256), 0, stream>>>(
        x, y, Wf, bf, Wg, bg, Wh, bh, fT, gT, hvb);
    attn_kernel<<<dim3(BB * 64), dim3(512), 0, stream>>>(
        fT, gT, hvb, x, gamma, out);
}